// Round 3
// baseline (618.581 us; speedup 1.0000x reference)
//
#include <hip/hip_runtime.h>
#include <math.h>

typedef unsigned long long ull;

#define N      96
#define NN     9216
#define LAT    256
#define ODIM   4656
#define CH     128      // k-chunks for encoder GEMV partials
#define RPC    72       // rows per chunk (128*72 = 9216)
#define ITERS  50
#define CB     48       // mpm blocks (2 output columns each)
#define CT     192      // threads per mpm block

// ---- workspace layout (float offsets) ----
#define WS_PART 0                       // [2][CH][LAT] = 65536
#define WS_OUTS 65536                   // 4656 sigmoid outputs
#define WS_KL   70192                   // 1
#define WS_BCE  70193                   // 1 (atomic accumulator)
#define WS_SLOT 70208                   // slots[2][48][8] ull = 1536 floats (64B-aligned)
#define WS_X    71808                   // 2 x 9216 ping-pong (col-major [a][i])
#define WS_CTL0 70192                   // zero range start
#define WS_CTLN 1552                    // zero range length (KL,BCE,pad,slots)

__device__ __forceinline__ int tri(int i, int j) {   // i <= j
    return i * N - i * (i - 1) / 2 + (j - i);
}

__device__ __forceinline__ int tri_row(int o) {
    int i = (int)floorf((193.0f - sqrtf((float)(37249 - 8 * o))) * 0.5f);
    i = max(0, min(95, i));
    while ((i + 1) * N - (i + 1) * i / 2 <= o) ++i;
    while (i * N - i * (i - 1) / 2 > o) --i;
    return i;
}

// ---- kA: encoder GEMV partials + control-word zeroing ----
__global__ __launch_bounds__(256) void kA_gemv(const float* __restrict__ h,
                                               const float* __restrict__ W1,
                                               const float* __restrict__ W2,
                                               float* __restrict__ ws) {
    __shared__ float hs[RPC];
    int t = threadIdx.x, c = blockIdx.x;
    if (c == 0) {
        for (int z = t; z < WS_CTLN; z += 256) ws[WS_CTL0 + z] = 0.f;
    }
    int k0 = c * RPC;
    if (t < RPC) hs[t] = h[k0 + t];
    __syncthreads();
    float a1 = 0.f, a2 = 0.f;
    #pragma unroll 4
    for (int kk = 0; kk < RPC; ++kk) {
        float hv = hs[kk];
        a1 = fmaf(hv, W1[(k0 + kk) * LAT + t], a1);
        a2 = fmaf(hv, W2[(k0 + kk) * LAT + t], a2);
    }
    ws[WS_PART + c * LAT + t]        = a1;
    ws[WS_PART + (CH + c) * LAT + t] = a2;
}

// ---- kB: reduce partials -> z ; KL ; decoder ; sigmoid ; BCE ----
__global__ __launch_bounds__(256) void kB_dec(const float* __restrict__ eps,
                                              const float* __restrict__ be11,
                                              const float* __restrict__ be12,
                                              const float* __restrict__ Wd1,
                                              const float* __restrict__ bd1,
                                              const float* __restrict__ Wd2,
                                              const float* __restrict__ bd2,
                                              const float* __restrict__ adj,
                                              float* __restrict__ ws) {
    __shared__ float zi[LAT];
    __shared__ float hid[LAT];
    __shared__ float red[256];
    int t = threadIdx.x;
    const float* p = ws + WS_PART;
    float mu = 0.f, ls = 0.f;
    #pragma unroll 8
    for (int c = 0; c < CH; ++c) {
        mu += p[c * LAT + t];
        ls += p[(CH + c) * LAT + t];
    }
    mu += be11[t];
    ls += be12[t];
    zi[t] = eps[t] * expf(0.5f * ls) + mu;
    red[t] = 1.0f + ls - mu * mu - expf(ls);
    __syncthreads();
    for (int s = 128; s > 0; s >>= 1) {
        if (t < s) red[t] += red[t + s];
        __syncthreads();
    }
    if (blockIdx.x == 0 && t == 0) ws[WS_KL] = -0.5f * red[0] / 9216.0f;
    __syncthreads();
    float acc = 0.f;
    #pragma unroll 8
    for (int k = 0; k < LAT; ++k) acc = fmaf(zi[k], Wd1[k * LAT + t], acc);
    hid[t] = fmaxf(acc + bd1[t], 0.f);
    __syncthreads();
    int o = blockIdx.x * 256 + t;
    float term = 0.f;
    if (o < ODIM) {
        float a2 = 0.f;
        #pragma unroll 8
        for (int k = 0; k < LAT; ++k) a2 = fmaf(hid[k], Wd2[k * ODIM + o], a2);
        float y = a2 + bd2[o];
        float s = 1.0f / (1.0f + expf(-y));
        ws[WS_OUTS + o] = s;
        int i = tri_row(o);
        int j = i + (o - (i * N - i * (i - 1) / 2));
        float inp = adj[i * N + j];
        float li = fmaxf(logf(inp), -100.0f);
        float l1 = fmaxf(log1pf(-inp), -100.0f);
        term = s * li + (1.0f - s) * l1;
    }
    red[t] = term;
    __syncthreads();
    for (int s = 128; s > 0; s >>= 1) {
        if (t < s) red[t] += red[t + s];
        __syncthreads();
    }
    if (t == 0) atomicAdd(ws + WS_BCE, red[0]);
}

// ---- flag-barrier poll: wait until all 48 slots in `bank` carry tag >= tag,
//      return 1/sqrt(sum of payloads). Wave 0 polls, result via LDS. ----
__device__ __forceinline__ float poll_inv(ull* bank, unsigned tag, float* s_inv) {
    int t = threadIdx.x;
    if (t < 64) {
        int lane = t;
        bool done = (lane >= CB);
        while (!__all(done)) {
            if (!done) {
                ull v = __hip_atomic_load(&bank[lane * 8], __ATOMIC_RELAXED,
                                          __HIP_MEMORY_SCOPE_AGENT);
                done = (unsigned)(v >> 32) >= tag;
            }
            __builtin_amdgcn_s_sleep(1);
        }
        float p = 0.f;
        if (lane < CB) {
            ull v2 = __hip_atomic_load(&bank[lane * 8], __ATOMIC_ACQUIRE,
                                       __HIP_MEMORY_SCOPE_AGENT);
            p = __uint_as_float((unsigned)v2);
        }
        #pragma unroll
        for (int off = 32; off > 0; off >>= 1) p += __shfl_xor(p, off);
        if (lane == 0) *s_inv = 1.0f / sqrtf(p);
    }
    __syncthreads();
    return *s_inv;
}

// ---- kC: self-contained MPM. Each block owns 2 output columns. ----
__global__ __launch_bounds__(CT, 1) void kC_mpm(const float* __restrict__ adj,
                                                float* __restrict__ ws,
                                                float* __restrict__ out) {
    __shared__ float xnT[N][97];        // xnT[a][i] = x[i][a], pad 97 -> conflict-free
    __shared__ float Brow[2][N];
    __shared__ float Scol[2][N];
    __shared__ float Mv[2][N];          // scratch: rec values (build), M[j] (loop)
    __shared__ float ds[N], drs[N], ft[N];
    __shared__ float ftr_sh[2];
    __shared__ float wred[4];
    __shared__ float s_inv;

    int t = threadIdx.x, bid = blockIdx.x;
    int jj = t % N, al = t / N;
    int a  = bid * 2 + al;

    const float* outs = ws + WS_OUTS;
    ull*  slots = (ull*)(ws + WS_SLOT);            // [2][48][8]
    float* xg0 = ws + WS_X;
    float* xg1 = ws + WS_X + NN;

    // ---- local build (no global matrices, no build barrier) ----
    if (t < N) {
        ds[t]  = adj[t * N + t];
        drs[t] = outs[tri(t, t)];
        const float4* ar = (const float4*)(adj + t * N);
        float s1 = 0.f;
        #pragma unroll
        for (int q = 0; q < N / 4; ++q) {
            float4 v = ar[q];
            s1 += v.x + v.y + v.z + v.w;
        }
        ft[t] = s1;
    }
    __syncthreads();
    {
        int lo = min(a, jj), hi = max(a, jj);
        Mv[al][jj] = outs[tri(lo, hi)];            // rec(a, jj)
    }
    __syncthreads();
    if (t < 2) {
        float s2 = 0.f;
        for (int b = 0; b < N; ++b) s2 += Mv[t][b];
        ftr_sh[t] = s2;
    }
    __syncthreads();
    Brow[al][jj] = (jj == a) ? 0.f : (Mv[al][jj] * drs[a]) * drs[jj];
    Scol[al][jj] = (ds[jj] * drs[a]) * (1.0f / (fabsf(ft[jj] - ftr_sh[al]) + 1.0f));

    // Aoff row jj in registers (constant across all iterations)
    float arow[N];
    {
        const float* arp = adj + jj * N;
        float di = ds[jj];
        #pragma unroll
        for (int j = 0; j < N; ++j)
            arow[j] = (j == jj) ? 0.f : (arp[j] * di) * ds[j];
    }
    __syncthreads();

    // ---- 50 MPM iterations ----
    float acc = 0.f;
    for (int it = 0; it < ITERS; ++it) {
        // stage normalized x into LDS (transposed)
        if (it == 0) {
            const float v0 = (float)(1.0 / 96.0);
            for (int f = t; f < NN; f += CT) xnT[f / N][f % N] = v0;
        } else {
            ull* bank = slots + (it & 1) * CB * 8;
            float inv = poll_inv(bank, (unsigned)it, &s_inv);
            const ull* src = (const ull*)(((it + 1) & 1) ? xg1 : xg0);
            for (int q = t; q < NN / 2; q += CT) {
                ull v = __hip_atomic_load((ull*)&src[q], __ATOMIC_RELAXED,
                                          __HIP_MEMORY_SCOPE_AGENT);
                int e = q * 2;
                int ac = e / N, i = e % N;
                xnT[ac][i]     = __uint_as_float((unsigned)v) * inv;
                xnT[ac][i + 1] = __uint_as_float((unsigned)(v >> 32)) * inv;
            }
        }
        __syncthreads();

        // phase B: M[jj, a] = max_b Brow[al][b] * x[jj][b]
        float m = 0.f;
        #pragma unroll
        for (int b = 0; b < N; ++b)
            m = fmaxf(m, Brow[al][b] * xnT[b][jj]);
        __syncthreads();                 // xnT[b][jj] reads done before Mv overwrite? (Mv != xnT, but Mv read below)
        Mv[al][jj] = m;
        __syncthreads();

        // phase C: x_new[jj, a] = x[jj][a]*Sd + sum_j Aoff[jj][j]*M[j, a]
        acc = xnT[a][jj] * Scol[al][jj];
        #pragma unroll
        for (int j = 0; j < N; ++j)
            acc = fmaf(arow[j], Mv[al][j], acc);

        // publish x_new (packed pairs, column-major), except last iteration
        float nx = __shfl_down(acc, 1);
        if (it < ITERS - 1 && (t & 1) == 0) {
            ull pv = (ull)__float_as_uint(acc) | ((ull)__float_as_uint(nx) << 32);
            float* dst = (it & 1) ? xg1 : xg0;
            __hip_atomic_store(&((ull*)dst)[(a * N + jj) >> 1], pv,
                               __ATOMIC_RELAXED, __HIP_MEMORY_SCOPE_AGENT);
        }

        // block ||x_new||^2 partial -> arrival flag payload
        float ss = acc * acc;
        #pragma unroll
        for (int off = 32; off > 0; off >>= 1) ss += __shfl_xor(ss, off);
        if ((t & 63) == 0) wred[t >> 6] = ss;
        __syncthreads();
        if (t == 0) {
            float s = wred[0] + wred[1] + wred[2];
            ull* bankN = slots + ((it + 1) & 1) * CB * 8;
            __hip_atomic_store(&bankN[bid * 8],
                               ((ull)(unsigned)(it + 1) << 32) | __float_as_uint(s),
                               __ATOMIC_RELEASE, __HIP_MEMORY_SCOPE_AGENT);
        }
        __syncthreads();
    }

    // ---- final normalize from registers, write output ----
    {
        ull* bank = slots + (ITERS & 1) * CB * 8;
        float invf = poll_inv(bank, (unsigned)ITERS, &s_inv);
        out[1 + jj * N + a] = acc * invf;
        if (bid == 0 && t == 0)
            out[0] = -(ws[WS_BCE] / 4656.0f) + ws[WS_KL];
    }
}

extern "C" void kernel_launch(void* const* d_in, const int* in_sizes, int n_in,
                              void* d_out, int out_size, void* d_ws, size_t ws_size,
                              hipStream_t stream) {
    const float* inf  = (const float*)d_in[0];
    const float* adj  = (const float*)d_in[1];
    const float* eps  = (const float*)d_in[2];
    const float* We11 = (const float*)d_in[3];
    const float* be11 = (const float*)d_in[4];
    const float* We12 = (const float*)d_in[5];
    const float* be12 = (const float*)d_in[6];
    const float* Wd1  = (const float*)d_in[7];
    const float* bd1  = (const float*)d_in[8];
    const float* Wd2  = (const float*)d_in[9];
    const float* bd2  = (const float*)d_in[10];
    float* ws  = (float*)d_ws;
    float* out = (float*)d_out;

    kA_gemv<<<CH, 256, 0, stream>>>(inf, We11, We12, ws);
    kB_dec <<<19, 256, 0, stream>>>(eps, be11, be12, Wd1, bd1, Wd2, bd2, adj, ws);
    kC_mpm <<<CB, CT, 0, stream>>>(adj, ws, out);
}

// Round 4
// 379.700 us; speedup vs baseline: 1.6291x; 1.6291x over previous
//
#include <hip/hip_runtime.h>
#include <math.h>

typedef unsigned long long ull;

#define N      96
#define NN     9216
#define LAT    256
#define ODIM   4656
#define CH     128      // k-chunks for encoder GEMV partials
#define RPC    72       // rows per chunk (128*72 = 9216)
#define ITERS  50
#define CB     12       // mpm blocks
#define CT     768      // threads per mpm block (12 waves)
#define CPB    8        // columns per block
#define WPT    6        // 8B words staged per thread (CT*WPT = NN/2)

#define SENT_F   -1.0f
#define SENT_U   0xBF800000u
#define SENTPAIR 0xBF800000BF800000ULL

// ---- workspace layout (float offsets) ----
#define WS_PART  0                      // [2][CH][LAT] = 65536
#define WS_OUTS  65536                  // 4656 sigmoid outputs
#define WS_KL    70192                  // 1
#define WS_BCE   70193                  // 1 (atomic accumulator)
#define WS_NSLOT 70208                  // [4][12][16] floats = 768 (64B/slot)
#define WS_XBUF  70976                  // [4][9216] floats, 8B aligned

__device__ __forceinline__ int tri(int i, int j) {   // i <= j
    return i * N - i * (i - 1) / 2 + (j - i);
}

__device__ __forceinline__ int tri_row(int o) {
    int i = (int)floorf((193.0f - sqrtf((float)(37249 - 8 * o))) * 0.5f);
    i = max(0, min(95, i));
    while ((i + 1) * N - (i + 1) * i / 2 <= o) ++i;
    while (i * N - i * (i - 1) / 2 > o) --i;
    return i;
}

// ---- kA: encoder GEMV partials + control/sentinel init ----
__global__ __launch_bounds__(256) void kA_gemv(const float* __restrict__ h,
                                               const float* __restrict__ W1,
                                               const float* __restrict__ W2,
                                               float* __restrict__ ws) {
    __shared__ float hs[RPC];
    int t = threadIdx.x, c = blockIdx.x;
    if (c == 0) {
        if (t < 2) ws[WS_KL + t] = 0.f;                        // KL, BCE
        for (int z = t; z < 4 * CB * 16; z += 256) ws[WS_NSLOT + z] = SENT_F;
        for (int z = t; z < 3 * NN; z += 256) ws[WS_XBUF + NN + z] = SENT_F;  // banks 1..3
    }
    int k0 = c * RPC;
    if (t < RPC) hs[t] = h[k0 + t];
    __syncthreads();
    float a1 = 0.f, a2 = 0.f;
    #pragma unroll 4
    for (int kk = 0; kk < RPC; ++kk) {
        float hv = hs[kk];
        a1 = fmaf(hv, W1[(k0 + kk) * LAT + t], a1);
        a2 = fmaf(hv, W2[(k0 + kk) * LAT + t], a2);
    }
    ws[WS_PART + c * LAT + t]        = a1;
    ws[WS_PART + (CH + c) * LAT + t] = a2;
}

// ---- kB: reduce partials -> z ; KL ; decoder ; sigmoid ; BCE ----
__global__ __launch_bounds__(256) void kB_dec(const float* __restrict__ eps,
                                              const float* __restrict__ be11,
                                              const float* __restrict__ be12,
                                              const float* __restrict__ Wd1,
                                              const float* __restrict__ bd1,
                                              const float* __restrict__ Wd2,
                                              const float* __restrict__ bd2,
                                              const float* __restrict__ adj,
                                              float* __restrict__ ws) {
    __shared__ float zi[LAT];
    __shared__ float hid[LAT];
    __shared__ float red[256];
    int t = threadIdx.x;
    const float* p = ws + WS_PART;
    float mu = 0.f, ls = 0.f;
    #pragma unroll 8
    for (int c = 0; c < CH; ++c) {
        mu += p[c * LAT + t];
        ls += p[(CH + c) * LAT + t];
    }
    mu += be11[t];
    ls += be12[t];
    zi[t] = eps[t] * expf(0.5f * ls) + mu;
    red[t] = 1.0f + ls - mu * mu - expf(ls);
    __syncthreads();
    for (int s = 128; s > 0; s >>= 1) {
        if (t < s) red[t] += red[t + s];
        __syncthreads();
    }
    if (blockIdx.x == 0 && t == 0) ws[WS_KL] = -0.5f * red[0] / 9216.0f;
    __syncthreads();
    float acc = 0.f;
    #pragma unroll 8
    for (int k = 0; k < LAT; ++k) acc = fmaf(zi[k], Wd1[k * LAT + t], acc);
    hid[t] = fmaxf(acc + bd1[t], 0.f);
    __syncthreads();
    int o = blockIdx.x * 256 + t;
    float term = 0.f;
    if (o < ODIM) {
        float a2 = 0.f;
        #pragma unroll 8
        for (int k = 0; k < LAT; ++k) a2 = fmaf(hid[k], Wd2[k * ODIM + o], a2);
        float y = a2 + bd2[o];
        float s = 1.0f / (1.0f + expf(-y));
        ws[WS_OUTS + o] = s;
        int i = tri_row(o);
        int j = i + (o - (i * N - i * (i - 1) / 2));
        float inp = adj[i * N + j];
        float li = fmaxf(logf(inp), -100.0f);
        float l1 = fmaxf(log1pf(-inp), -100.0f);
        term = s * li + (1.0f - s) * l1;
    }
    red[t] = term;
    __syncthreads();
    for (int s = 128; s > 0; s >>= 1) {
        if (t < s) red[t] += red[t + s];
        __syncthreads();
    }
    if (t == 0) atomicAdd(ws + WS_BCE, red[0]);
}

// ---- kC: MPM, 12 blocks x 768 threads, sentinel-word sync ----
__global__ __launch_bounds__(CT, 3) void kC_mpm(const float* __restrict__ adj,
                                                float* __restrict__ ws,
                                                float* __restrict__ out) {
    __shared__ float xnT[N][97];        // xnT[col a][row i] = x[i][a]
    __shared__ float Brow[CPB][N];
    __shared__ float Scol[CPB][N];
    __shared__ float Mv[CPB][N];
    __shared__ float ds[N], drs[N], ft[N];
    __shared__ float ftr_sh[CPB];
    __shared__ float wred[CT / 64];
    __shared__ float s_inv;

    int t = threadIdx.x, bid = blockIdx.x;
    int jj = t % N, al = t / N;          // al 0..7
    int a  = bid * CPB + al;             // global column

    const float* outs = ws + WS_OUTS;
    float* xbuf  = ws + WS_XBUF;         // [4][NN]
    float* nslot = ws + WS_NSLOT;        // [4][CB][16]

    // ---- local build ----
    if (t < N) {
        ds[t]  = adj[t * N + t];
        drs[t] = outs[tri(t, t)];
        const float4* ar = (const float4*)(adj + t * N);
        float s1 = 0.f;
        #pragma unroll
        for (int q = 0; q < N / 4; ++q) {
            float4 v = ar[q];
            s1 += v.x + v.y + v.z + v.w;
        }
        ft[t] = s1;
    }
    __syncthreads();
    {
        int lo = min(a, jj), hi = max(a, jj);
        Mv[al][jj] = outs[tri(lo, hi)];            // rec(a, jj)
    }
    __syncthreads();
    if (t < CPB) {
        float s2 = 0.f;
        for (int b = 0; b < N; ++b) s2 += Mv[t][b];
        ftr_sh[t] = s2;
    }
    __syncthreads();
    Brow[al][jj] = (jj == a) ? 0.f : (Mv[al][jj] * drs[a]) * drs[jj];
    Scol[al][jj] = (ds[jj] * drs[a]) * (1.0f / (fabsf(ft[jj] - ftr_sh[al]) + 1.0f));

    // Aoff row jj in registers (constant across all iterations)
    float arow[N];
    {
        const float* arp = adj + jj * N;
        float di = ds[jj];
        #pragma unroll
        for (int j = 0; j < N; ++j)
            arow[j] = (j == jj) ? 0.f : (arp[j] * di) * ds[j];
    }
    __syncthreads();

    // ---- 50 MPM iterations ----
    float acc = 0.f;
    for (int s = 0; s < ITERS; ++s) {
        if (s == 0) {
            const float v0 = (float)(1.0 / 96.0);
            for (int f = t; f < NN; f += CT) xnT[f / N][f % N] = v0;
            if (t == 0) s_inv = 1.0f;              // ||x0|| == 1 exactly
        } else {
            // stage raw x_s: poll data words until non-sentinel
            const ull* src = (const ull*)(xbuf + (s & 3) * NN);
            ull v[WPT];
            bool ok = false;
            while (!ok) {
                ok = true;
                #pragma unroll
                for (int k = 0; k < WPT; ++k)
                    v[k] = __hip_atomic_load(&src[k * CT + t], __ATOMIC_RELAXED,
                                             __HIP_MEMORY_SCOPE_AGENT);
                #pragma unroll
                for (int k = 0; k < WPT; ++k) ok &= (v[k] != SENTPAIR);
                if (!ok) __builtin_amdgcn_s_sleep(1);
            }
            #pragma unroll
            for (int k = 0; k < WPT; ++k) {
                int e = (k * CT + t) * 2;
                int ac = e / N, i = e % N;
                xnT[ac][i]     = __uint_as_float((unsigned)v[k]);
                xnT[ac][i + 1] = __uint_as_float((unsigned)(v[k] >> 32));
            }
            // norm poll (wave 0, lanes < CB); overlaps nothing critical
            if (t < 64) {
                float pv = 0.f;
                bool done = (t >= CB);
                const unsigned* np = (const unsigned*)(nslot + (s & 3) * CB * 16);
                while (!__all(done)) {
                    if (!done) {
                        unsigned u = __hip_atomic_load(&np[t * 16], __ATOMIC_RELAXED,
                                                       __HIP_MEMORY_SCOPE_AGENT);
                        if (u != SENT_U) { pv = __uint_as_float(u); done = true; }
                    }
                    __builtin_amdgcn_s_sleep(1);
                }
                #pragma unroll
                for (int off = 8; off > 0; off >>= 1) pv += __shfl_xor(pv, off, 16);
                if (t == 0) s_inv = 1.0f / sqrtf(pv);
            }
        }
        __syncthreads();

        // phase B: M[jj, a] = max_b Brow[al][b] * x[jj][b]   (raw x)
        float m = 0.f;
        #pragma unroll
        for (int b = 0; b < N; ++b)
            m = fmaxf(m, Brow[al][b] * xnT[b][jj]);
        __syncthreads();
        Mv[al][jj] = m;
        __syncthreads();

        // phase C: raw accumulate, then scale once by 1/||x_s||
        float r = xnT[a][jj] * Scol[al][jj];
        #pragma unroll
        for (int j = 0; j < N; ++j)
            r = fmaf(arow[j], Mv[al][j], r);
        acc = r * s_inv;

        // publish x_{s+1} pairs (relaxed, fire-and-forget)
        float nx = __shfl_down(acc, 1);
        if (s < ITERS - 1 && (t & 1) == 0) {
            ull pv = (ull)__float_as_uint(acc) | ((ull)__float_as_uint(nx) << 32);
            __hip_atomic_store((ull*)(xbuf + ((s + 1) & 3) * NN) + ((a * N + jj) >> 1),
                               pv, __ATOMIC_RELAXED, __HIP_MEMORY_SCOPE_AGENT);
        }

        // block partial of ||x_{s+1}||^2 -> sentinel slot
        float ss = acc * acc;
        #pragma unroll
        for (int off = 32; off > 0; off >>= 1) ss += __shfl_xor(ss, off);
        if ((t & 63) == 0) wred[t >> 6] = ss;
        __syncthreads();
        if (t == 0) {
            float sum = 0.f;
            #pragma unroll
            for (int w = 0; w < CT / 64; ++w) sum += wred[w];
            __hip_atomic_store((unsigned*)(nslot + ((s + 1) & 3) * CB * 16 + bid * 16),
                               __float_as_uint(sum), __ATOMIC_RELAXED,
                               __HIP_MEMORY_SCOPE_AGENT);
        }

        // sentinel-refresh own slice of bank (s+3)&3 (consumed at stage s+3)
        if (s < ITERS - 3 && (t & 1) == 0) {
            __hip_atomic_store((ull*)(xbuf + ((s + 3) & 3) * NN) + ((a * N + jj) >> 1),
                               SENTPAIR, __ATOMIC_RELAXED, __HIP_MEMORY_SCOPE_AGENT);
        }
        if (s < ITERS - 2 && t == 0) {
            __hip_atomic_store((unsigned*)(nslot + ((s + 3) & 3) * CB * 16 + bid * 16),
                               SENT_U, __ATOMIC_RELAXED, __HIP_MEMORY_SCOPE_AGENT);
        }
        __syncthreads();   // also protects xnT/s_inv against next-iter staging
    }

    // ---- final normalize (poll ||x_50||), write output ----
    if (t < 64) {
        float pv = 0.f;
        bool done = (t >= CB);
        const unsigned* np = (const unsigned*)(nslot + (ITERS & 3) * CB * 16);
        while (!__all(done)) {
            if (!done) {
                unsigned u = __hip_atomic_load(&np[t * 16], __ATOMIC_RELAXED,
                                               __HIP_MEMORY_SCOPE_AGENT);
                if (u != SENT_U) { pv = __uint_as_float(u); done = true; }
            }
            __builtin_amdgcn_s_sleep(1);
        }
        #pragma unroll
        for (int off = 8; off > 0; off >>= 1) pv += __shfl_xor(pv, off, 16);
        if (t == 0) s_inv = 1.0f / sqrtf(pv);
    }
    __syncthreads();
    out[1 + jj * N + a] = acc * s_inv;
    if (bid == 0 && t == 0)
        out[0] = -(ws[WS_BCE] / 4656.0f) + ws[WS_KL];
}

extern "C" void kernel_launch(void* const* d_in, const int* in_sizes, int n_in,
                              void* d_out, int out_size, void* d_ws, size_t ws_size,
                              hipStream_t stream) {
    const float* inf  = (const float*)d_in[0];
    const float* adj  = (const float*)d_in[1];
    const float* eps  = (const float*)d_in[2];
    const float* We11 = (const float*)d_in[3];
    const float* be11 = (const float*)d_in[4];
    const float* We12 = (const float*)d_in[5];
    const float* be12 = (const float*)d_in[6];
    const float* Wd1  = (const float*)d_in[7];
    const float* bd1  = (const float*)d_in[8];
    const float* Wd2  = (const float*)d_in[9];
    const float* bd2  = (const float*)d_in[10];
    float* ws  = (float*)d_ws;
    float* out = (float*)d_out;

    kA_gemv<<<CH, 256, 0, stream>>>(inf, We11, We12, ws);
    kB_dec <<<19, 256, 0, stream>>>(eps, be11, be12, Wd1, bd1, Wd2, bd2, adj, ws);
    kC_mpm <<<CB, CT, 0, stream>>>(adj, ws, out);
}